// Round 1
// baseline (3237.824 us; speedup 1.0000x reference)
//
#include <hip/hip_runtime.h>
#include <math.h>

#define BATCH   8
#define NPTS    32768
#define FDIM    32
#define NGROUP  1024
#define GSIZE   32
#define KLANE   8       // per-lane candidate list length in KNN

// FPS: R15 restructure -- 2 blocks/batch x 512 thr x 32 pts/thr = 32768.
// (R13 best measured: 2872 us with 8 blocks/batch.)
#define NBLK    2
#define FTPB    512
#define CHUNK   (NPTS / NBLK)     // 16384 points per block
#define PPT     (CHUNK / FTPB)    // 32 points per thread (128 data VGPRs)
#define NFPSBLK (BATCH * NBLK)    // 16 producer blocks (first in grid)
#define SLOTSTR 8                 // u64 stride: one 64B line per slot
#define KNNQPB  8                 // 8 queries (waves) per 512-thr knn block
#define NKNNBLK ((BATCH * NGROUP) / KNNQPB)   // 1024 consumer blocks

// Exact float32 distance in the reference's association: ((dx^2+dy^2)+dz^2),
// contraction blocked so bits match the numpy ref (argmax stability).
__device__ __forceinline__ float dist2f(float ax, float ay, float az,
                                        float bx, float by, float bz) {
  float dx = __fsub_rn(ax, bx);
  float dy = __fsub_rn(ay, by);
  float dz = __fsub_rn(az, bz);
  return __fadd_rn(__fadd_rn(__fmul_rn(dx, dx), __fmul_rn(dy, dy)),
                   __fmul_rn(dz, dz));
}

// ---------------------------------------------------------------------------
// R15 theory: R13's ~2.8 us/iter floor decomposes as ~400 cyc update VALU +
// ~400 cyc reduce/barriers + ~5800 cyc consensus. The consensus cost is the
// 8-writer serialization on ONE 64B line (slots (b<<3)+bk share a line -> L2
// line ping-pongs through 8 CUs' stores) plus max-of-8 straggler spread --
// NOT the bare store->observe RT. So trade VALU for writers: 2 blocks/batch,
// 32 pts/thread in VGPRs (launch_bounds(512,2) -> <=256 VGPR, no spill).
// Each block stores its candidate to a PRIVATE 64B line (1 writer, 1 remote
// poller, no ping-pong, XCD-local under %8 RR pairing of blocks b and b+8)
// and polls exactly one remote line. Predicted period ~1536 (update) + ~400
// (argmax+barriers) + ~400 (store->observe) + ~200 (coord load) ~= 1.0-1.3
// us/iter -> dur ~1.2-1.5 ms. Consumers: backoff rescaled tq>>2 -> tq>>3 for
// the faster publish rate; consumer occupancy drops (shared VGPR count) but
// KNN has ~10x slack and pipelines through CU slots in dispatch order.
// ---------------------------------------------------------------------------
__global__ __launch_bounds__(FTPB, 2) void fused_kernel(
    const float* __restrict__ coord, const float* __restrict__ feat,
    const int* __restrict__ labels,
    unsigned long long* __restrict__ slots,   // [2][16] u64, 64B-strided, pre-zeroed
    int* __restrict__ s_idx_ws,               // [8192] idx+1, pre-zeroed
    float* __restrict__ out) {
  __shared__ float redv[8];
  __shared__ int   redp[8];
  __shared__ unsigned long long bcast;

  const int bx   = blockIdx.x;
  const int tid  = threadIdx.x;
  const int lane = tid & 63;
  const int wid  = tid >> 6;          // 0..7

  if (bx < NFPSBLK) {
    // ===================== FPS (producer) =====================
    const int b    = bx & 7;          // batch (XCD-local under %8 mapping)
    const int bk   = bx >> 3;         // block within batch: 0 or 1
    const float* __restrict__ c = coord + (size_t)b * NPTS * 3;
    const float3* __restrict__ c3 = (const float3*)c;
    const int pbase = bk * CHUNK + tid;

    float px[PPT], py[PPT], pz[PPT], pd[PPT];

    // Init: distance to batch point 0; local argmax (ascending index +
    // strict > == np.argmax lowest-index tie-break).
    float qx = c[0], qy = c[1], qz = c[2];
    float bestv = -1.0f; int besti = 0;
    #pragma unroll
    for (int i = 0; i < PPT; ++i) {
      int p = pbase + i * FTPB;
      float3 v = c3[p];
      px[i] = v.x; py[i] = v.y; pz[i] = v.z;
      float t2 = dist2f(v.x, v.y, v.z, qx, qy, qz);
      pd[i] = t2;
      if (t2 > bestv) { bestv = t2; besti = i; }
    }

    if (bk == 0 && tid == 0)
      __hip_atomic_store(&s_idx_ws[b * NGROUP + 0], 1, __ATOMIC_RELAXED,
                         __HIP_MEMORY_SCOPE_AGENT);   // idx 0, +1 encoding

    for (int t = 1; t < NGROUP; ++t) {
      // Wave-level argmax (max value, tie -> min index).
      float v = bestv; int p = pbase + (besti << 9);   // FTPB = 512
      #pragma unroll
      for (int m = 1; m < 64; m <<= 1) {
        float ov = __shfl_xor(v, m, 64);
        int   op = __shfl_xor(p, m, 64);
        if (ov > v || (ov == v && op < p)) { v = ov; p = op; }
      }
      if (lane == 0) { redv[wid] = v; redp[wid] = p; }
      __syncthreads();   // B1

      if (wid == 0) {
        float gv = redv[lane & 7]; int gp = redp[lane & 7];
        #pragma unroll
        for (int m = 1; m < 8; m <<= 1) {
          float ov = __shfl_xor(gv, m, 64);
          int   op = __shfl_xor(gp, m, 64);
          if (ov > gv || (ov == gv && op < gp)) { gv = ov; gp = op; }
        }
        if (lane == 0) {
          unsigned long long* base =
              slots + (size_t)(t & 1) * (BATCH * NBLK * SLOTSTR);
          unsigned long long own = ((unsigned long long)t << 47)
                                 | ((unsigned long long)__float_as_uint(gv) << 15)
                                 | (unsigned long long)(0x7FFF - gp);
          __hip_atomic_store(base + (b * NBLK + bk) * SLOTSTR, own,
                             __ATOMIC_RELEASE, __HIP_MEMORY_SCOPE_AGENT);
          const unsigned long long* rs = base + (b * NBLK + (bk ^ 1)) * SLOTSTR;
          unsigned long long rem;
          do {
            rem = __hip_atomic_load(rs, __ATOMIC_ACQUIRE,
                                    __HIP_MEMORY_SCOPE_AGENT);
          } while ((int)(rem >> 47) != t);
          bcast = (rem > own) ? rem : own;   // dist asc, tie -> lower idx
        }
      }
      __syncthreads();   // B2

      const unsigned long long wpk = bcast;
      const int gsel = 0x7FFF - (int)(wpk & 0x7FFF);
      if (bk == 0 && tid == 0)
        __hip_atomic_store(&s_idx_ws[b * NGROUP + t], gsel + 1,
                           __ATOMIC_RELAXED, __HIP_MEMORY_SCOPE_AGENT);
      if (t == NGROUP - 1) break;

      float3 q = c3[gsel];
      qx = q.x; qy = q.y; qz = q.z;
      bestv = -1.0f; besti = 0;
      #pragma unroll
      for (int i = 0; i < PPT; ++i) {
        float t2 = dist2f(px[i], py[i], pz[i], qx, qy, qz);
        float nd = fminf(pd[i], t2);
        pd[i] = nd;
        if (nd > bestv) { bestv = nd; besti = i; }
      }
    }
    return;
  }

  // ===================== KNN (consumer) =====================
  const int qid = (bx - NFPSBLK) * KNNQPB + wid;   // 0..8191
  const int b   = qid >> 10;
  const float* __restrict__ c = coord + (size_t)b * NPTS * 3;

  // Conservative backoff (~1/3 of estimated publish time at ~1.1 us/iter),
  // then slow spin. s_sleep counts CORE CLOCKS (R12 lesson).
  const int tq = qid & (NGROUP - 1);
  int enc = __hip_atomic_load(&s_idx_ws[qid], __ATOMIC_RELAXED,
                              __HIP_MEMORY_SCOPE_AGENT);
  for (int i = tq >> 3; i > 0 && enc == 0; --i) {
    __builtin_amdgcn_s_sleep(127);
    enc = __hip_atomic_load(&s_idx_ws[qid], __ATOMIC_RELAXED,
                            __HIP_MEMORY_SCOPE_AGENT);
  }
  while (enc == 0) {
    __builtin_amdgcn_s_sleep(64);
    enc = __hip_atomic_load(&s_idx_ws[qid], __ATOMIC_RELAXED,
                            __HIP_MEMORY_SCOPE_AGENT);
  }
  const int sp = __builtin_amdgcn_readfirstlane(enc - 1);
  const int gq = b * NPTS + sp;
  const float qx = coord[(size_t)gq * 3 + 0];
  const float qy = coord[(size_t)gq * 3 + 1];
  const float qz = coord[(size_t)gq * 3 + 2];

  // Per-lane ascending top-8 (value, index), static indexing only.
  float lv[KLANE]; int li[KLANE];
  #pragma unroll
  for (int j = 0; j < KLANE; ++j) { lv[j] = 1e30f; li[j] = 0x7fffffff; }

  // Branchless sorted insert; strict < keeps equal-distance earlier (lower)
  // indices first, matching lax.top_k tie order.
#define INSERT(D2, P) \
  if ((D2) < lv[KLANE - 1]) { \
    _Pragma("unroll") \
    for (int j = KLANE - 1; j >= 1; --j) { \
      bool up = (D2) < lv[j - 1]; \
      float nv = up ? lv[j - 1] : (((D2) < lv[j]) ? (D2) : lv[j]); \
      int   ni = up ? li[j - 1] : (((D2) < lv[j]) ? (P)  : li[j]); \
      lv[j] = nv; li[j] = ni; \
    } \
    if ((D2) < lv[0]) { lv[0] = (D2); li[0] = (P); } \
  }

  for (int s = 0; s < NPTS / 256; ++s) {   // 128 iterations, 4 pts/lane
    int p = (s << 8) | (lane << 2);
    const float4* c4 = (const float4*)(c + (size_t)p * 3);
    float4 f0 = c4[0], f1 = c4[1], f2 = c4[2];
    float dA = dist2f(f0.x, f0.y, f0.z, qx, qy, qz);
    float dB = dist2f(f0.w, f1.x, f1.y, qx, qy, qz);
    float dC = dist2f(f1.z, f1.w, f2.x, qx, qy, qz);
    float dD = dist2f(f2.y, f2.z, f2.w, qx, qy, qz);
    INSERT(dA, p);
    INSERT(dB, p + 1);
    INSERT(dC, p + 2);
    INSERT(dD, p + 3);
  }
#undef INSERT

  // Extract the 32 globally smallest (ascending, tie -> lower index).
  // Round 0 is the query itself (d2 == 0), excluded from the angle mean
  // like angles[:, :, 1:].
  int nbp = 0;
  for (int r = 0; r < GSIZE; ++r) {
    float mv = lv[0]; int mp = li[0];
    #pragma unroll
    for (int m = 1; m < 64; m <<= 1) {
      float ov = __shfl_xor(mv, m, 64);
      int   op = __shfl_xor(mp, m, 64);
      if (ov < mv || (ov == mv && op < mp)) { mv = ov; mp = op; }
    }
    if (lane == r) nbp = mp;
    if (lv[0] == mv && li[0] == mp) {  // unique winner pops its head
      #pragma unroll
      for (int j = 0; j < KLANE - 1; ++j) { lv[j] = lv[j + 1]; li[j] = li[j + 1]; }
      lv[KLANE - 1] = 1e30f; li[KLANE - 1] = 0x7fffffff;
    }
  }

  // Angle for lanes 1..31: theta = 2*atan2(||a*|b| - |a|*b||, ||a*|b| + |a|*b||)
  const float* aRow = feat + (size_t)gq * FDIM;
  float my_a = (lane < FDIM) ? aRow[lane] : 0.0f;

  float ang = 0.0f;
  if (lane >= 1 && lane < GSIZE) {
    const float4* a4 = (const float4*)aRow;
    const float4* b4 = (const float4*)(feat + ((size_t)b * NPTS + nbp) * FDIM);
    float4 av[FDIM / 4], bv[FDIM / 4];
    float aa = 0.0f, bb = 0.0f;
    #pragma unroll
    for (int k = 0; k < FDIM / 4; ++k) {
      av[k] = a4[k]; bv[k] = b4[k];
      aa += av[k].x * av[k].x + av[k].y * av[k].y + av[k].z * av[k].z + av[k].w * av[k].w;
      bb += bv[k].x * bv[k].x + bv[k].y * bv[k].y + bv[k].z * bv[k].z + bv[k].w * bv[k].w;
    }
    float an = sqrtf(aa), bn = sqrtf(bb);
    float num2 = 0.0f, den2 = 0.0f;
    #pragma unroll
    for (int k = 0; k < FDIM / 4; ++k) {
      float n0 = av[k].x * bn - an * bv[k].x, dd0 = av[k].x * bn + an * bv[k].x;
      float n1 = av[k].y * bn - an * bv[k].y, dd1 = av[k].y * bn + an * bv[k].y;
      float n2 = av[k].z * bn - an * bv[k].z, dd2 = av[k].z * bn + an * bv[k].z;
      float n3 = av[k].w * bn - an * bv[k].w, dd3 = av[k].w * bn + an * bv[k].w;
      num2 += n0 * n0 + n1 * n1 + n2 * n2 + n3 * n3;
      den2 += dd0 * dd0 + dd1 * dd1 + dd2 * dd2 + dd3 * dd3;
    }
    ang = 2.0f * atan2f(sqrtf(num2), sqrtf(den2));
  }

  // Wave sum of the 31 angles -> p_curv everywhere.
  float tot = ang;
  #pragma unroll
  for (int m = 1; m < 64; m <<= 1) tot += __shfl_xor(tot, m, 64);
  float p_curv = tot / 31.0f;

  // Outputs (flat concatenation, all as float32).
  float* out_xyz  = out;                              // 8192*3
  float* out_feat = out + (size_t)BATCH * NGROUP * 3; // 8192*33
  float* out_sw   = out_feat + (size_t)BATCH * NGROUP * (FDIM + 1);
  float* out_lab  = out_sw  + (size_t)BATCH * NGROUP;
  float* out_sif  = out_lab + (size_t)BATCH * NGROUP;

  if (lane < FDIM)  out_feat[(size_t)qid * (FDIM + 1) + lane] = my_a;
  if (lane == FDIM) out_feat[(size_t)qid * (FDIM + 1) + FDIM] = p_curv;
  if (lane == 0) {
    out_xyz[(size_t)qid * 3 + 0] = qx;
    out_xyz[(size_t)qid * 3 + 1] = qy;
    out_xyz[(size_t)qid * 3 + 2] = qz;
    out_sw[qid]  = (p_curv > 0.087266f) ? 1.0f : 0.0f;
    out_lab[qid] = (float)labels[gq];
    out_sif[qid] = (float)gq;   // s_idx + b*N
  }
}

extern "C" void kernel_launch(void* const* d_in, const int* in_sizes, int n_in,
                              void* d_out, int out_size, void* d_ws, size_t ws_size,
                              hipStream_t stream) {
  const float* coord  = (const float*)d_in[0];
  const float* feat   = (const float*)d_in[1];
  const int*   labels = (const int*)d_in[2];

  // ws layout: [2][16] u64 ping-pong slots (64B-strided, one line per slot),
  // then [8192] int s_idx (+1 encoded, 0 = unpublished). Both start zeroed.
  unsigned long long* slots = (unsigned long long*)d_ws;
  int* s_idx_ws = (int*)((char*)d_ws +
                         2 * BATCH * NBLK * SLOTSTR * sizeof(unsigned long long));
  const size_t zbytes = 2 * BATCH * NBLK * SLOTSTR * sizeof(unsigned long long)
                      + (size_t)BATCH * NGROUP * sizeof(int);

  hipMemsetAsync(d_ws, 0, zbytes, stream);
  fused_kernel<<<NFPSBLK + NKNNBLK, FTPB, 0, stream>>>(
      coord, feat, labels, slots, s_idx_ws, (float*)d_out);
}

// Round 2
// 2750.470 us; speedup vs baseline: 1.1772x; 1.1772x over previous
//
#include <hip/hip_runtime.h>
#include <math.h>

#define BATCH   8
#define NPTS    32768
#define FDIM    32
#define NGROUP  1024
#define GSIZE   32
#define KLANE   8       // per-lane candidate list length in KNN

// FPS: R16 -- 4 blocks/batch x 512 thr x 16 pts/thr (NAMED SCALARS).
// R15 lesson: float arrays[32] were demoted to scratch (VGPR_Count=88 < 128
// data floats needed) -- the private-line consensus was never actually
// measured. R16 removes the confound: X16 macro scalars (mem2reg-proof),
// ~110 VGPR total, and 4 writers instead of 2 to keep the update chain at
// ~640 cyc.
#define NBLK    4
#define FTPB    512
#define CHUNK   (NPTS / NBLK)     // 8192 points per block
#define PPT     (CHUNK / FTPB)    // 16 points per thread (64 named scalars)
#define NFPSBLK (BATCH * NBLK)    // 32 producer blocks (first in grid)
#define SLOTSTR 8                 // u64 stride: one 64B line per slot
#define KNNQPB  8                 // 8 queries (waves) per 512-thr knn block
#define NKNNBLK ((BATCH * NGROUP) / KNNQPB)   // 1024 consumer blocks

// Exact float32 distance in the reference's association: ((dx^2+dy^2)+dz^2),
// contraction blocked so bits match the numpy ref (argmax stability).
__device__ __forceinline__ float dist2f(float ax, float ay, float az,
                                        float bx, float by, float bz) {
  float dx = __fsub_rn(ax, bx);
  float dy = __fsub_rn(ay, by);
  float dz = __fsub_rn(az, bz);
  return __fadd_rn(__fadd_rn(__fmul_rn(dx, dx), __fmul_rn(dy, dy)),
                   __fmul_rn(dz, dz));
}

#define X16(M) M(0) M(1) M(2) M(3) M(4) M(5) M(6) M(7) \
               M(8) M(9) M(10) M(11) M(12) M(13) M(14) M(15)

// ---------------------------------------------------------------------------
// Consensus (R16): R13's period (~6750 cyc) decomposed as ~450 update + ~400
// reduce + ~5900 consensus, where all 8 writers of a batch stored into ONE
// 64B line (slots (b<<3)+bk contiguous) -> the line serializes through 8
// CUs' release-stores in L2 plus max-of-8 straggler spread. R16: each block
// owns a PRIVATE 64B-strided slot (1 writer/line, no ping-pong), lanes 0..3
// of wave 0 acquire-poll the batch's 4 slots (4 distinct lines), 2-round
// shuffle max, LDS bcast. All 4 blocks of batch b sit on XCD b (bx&7 under
// %8 RR) -> XCD-local L2 propagation (~200-400 cyc RT).
// Predicted period ~640 (update, 16pt/thr VALU) + ~400 (argmax+barriers)
// + ~400 (store->observe) + ~200 (coord reload) ~= 1700 cyc ~= 0.7-0.9 us.
// If it lands back at ~2.6-2.9 us/iter with clean VGPRs, the writer-count
// axis is closed and the floor is the bare one-line propagation latency.
// ---------------------------------------------------------------------------
__global__ __launch_bounds__(FTPB) void fused_kernel(
    const float* __restrict__ coord, const float* __restrict__ feat,
    const int* __restrict__ labels,
    unsigned long long* __restrict__ slots,   // [2][32] u64, 64B-strided, pre-zeroed
    int* __restrict__ s_idx_ws,               // [8192] idx+1, pre-zeroed
    float* __restrict__ out) {
  __shared__ float redv[8];
  __shared__ int   redp[8];
  __shared__ unsigned long long bcast;

  const int bx   = blockIdx.x;
  const int tid  = threadIdx.x;
  const int lane = tid & 63;
  const int wid  = tid >> 6;          // 0..7

  if (bx < NFPSBLK) {
    // ===================== FPS (producer) =====================
    const int b    = bx & 7;          // batch (XCD-local under %8 mapping)
    const int bk   = bx >> 3;         // block within batch: 0..3
    const float* __restrict__ c = coord + (size_t)b * NPTS * 3;
    const float3* __restrict__ c3 = (const float3*)c;
    const int pbase = bk * CHUNK + tid;

#define DECL16(i) float x##i, y##i, z##i, d##i;
    X16(DECL16)
#undef DECL16

    // Init: distance to batch point 0; local argmax (ascending index +
    // strict > == np.argmax lowest-index tie-break).
    float qx = c[0], qy = c[1], qz = c[2];
    float bestv = -1.0f; int bestp = 0;
#define LOAD16(i) { int p = pbase + (i) * FTPB; float3 v = c3[p];            \
    x##i = v.x; y##i = v.y; z##i = v.z;                                      \
    float t2 = dist2f(v.x, v.y, v.z, qx, qy, qz); d##i = t2;                 \
    if (t2 > bestv) { bestv = t2; bestp = p; } }
    X16(LOAD16)
#undef LOAD16

    if (bk == 0 && tid == 0)
      __hip_atomic_store(&s_idx_ws[b * NGROUP + 0], 1, __ATOMIC_RELAXED,
                         __HIP_MEMORY_SCOPE_AGENT);   // idx 0, +1 encoding

    for (int t = 1; t < NGROUP; ++t) {
      // Wave-level argmax (max value, tie -> min index).
      float v = bestv; int p = bestp;
      #pragma unroll
      for (int m = 1; m < 64; m <<= 1) {
        float ov = __shfl_xor(v, m, 64);
        int   op = __shfl_xor(p, m, 64);
        if (ov > v || (ov == v && op < p)) { v = ov; p = op; }
      }
      if (lane == 0) { redv[wid] = v; redp[wid] = p; }
      __syncthreads();   // B1

      if (wid == 0) {
        float gv = redv[lane & 7]; int gp = redp[lane & 7];
        #pragma unroll
        for (int m = 1; m < 8; m <<= 1) {
          float ov = __shfl_xor(gv, m, 64);
          int   op = __shfl_xor(gp, m, 64);
          if (ov > gv || (ov == gv && op < gp)) { gv = ov; gp = op; }
        }
        unsigned long long* base =
            slots + (size_t)(t & 1) * (BATCH * NBLK * SLOTSTR);
        if (lane == 0) {
          unsigned long long own = ((unsigned long long)t << 47)
                                 | ((unsigned long long)__float_as_uint(gv) << 15)
                                 | (unsigned long long)(0x7FFF - gp);
          __hip_atomic_store(base + (b * NBLK + bk) * SLOTSTR, own,
                             __ATOMIC_RELEASE, __HIP_MEMORY_SCOPE_AGENT);
        }
        unsigned long long pk2 = 0;
        if (lane < NBLK) {   // 4 lanes, 4 distinct 64B lines
          const unsigned long long* sl = base + (b * NBLK + lane) * SLOTSTR;
          do {
            pk2 = __hip_atomic_load(sl, __ATOMIC_ACQUIRE,
                                    __HIP_MEMORY_SCOPE_AGENT);
          } while ((int)(pk2 >> 47) != t);
        }
        #pragma unroll
        for (int m = 1; m < NBLK; m <<= 1) {
          unsigned long long o = __shfl_xor(pk2, m, 64);
          if (o > pk2) pk2 = o;
        }
        if (lane == 0) bcast = pk2;
      }
      __syncthreads();   // B2

      const unsigned long long wpk = bcast;
      const int gsel = 0x7FFF - (int)(wpk & 0x7FFF);
      if (bk == 0 && tid == 0)
        __hip_atomic_store(&s_idx_ws[b * NGROUP + t], gsel + 1,
                           __ATOMIC_RELAXED, __HIP_MEMORY_SCOPE_AGENT);
      if (t == NGROUP - 1) break;

      float3 q = c3[gsel];
      qx = q.x; qy = q.y; qz = q.z;
      bestv = -1.0f; bestp = 0;
#define UPD16(i) { float t2 = dist2f(x##i, y##i, z##i, qx, qy, qz);          \
    float nd = fminf(d##i, t2); d##i = nd;                                   \
    if (nd > bestv) { bestv = nd; bestp = pbase + (i) * FTPB; } }
      X16(UPD16)
#undef UPD16
    }
    return;
  }

  // ===================== KNN (consumer) =====================
  const int qid = (bx - NFPSBLK) * KNNQPB + wid;   // 0..8191
  const int b   = qid >> 10;
  const float* __restrict__ c = coord + (size_t)b * NPTS * 3;

  // Conservative backoff (~1/2 of estimated publish time at ~0.9 us/iter),
  // then slow spin. s_sleep counts CORE CLOCKS (R12 lesson).
  const int tq = qid & (NGROUP - 1);
  int enc = __hip_atomic_load(&s_idx_ws[qid], __ATOMIC_RELAXED,
                              __HIP_MEMORY_SCOPE_AGENT);
  for (int i = tq >> 3; i > 0 && enc == 0; --i) {
    __builtin_amdgcn_s_sleep(127);
    enc = __hip_atomic_load(&s_idx_ws[qid], __ATOMIC_RELAXED,
                            __HIP_MEMORY_SCOPE_AGENT);
  }
  while (enc == 0) {
    __builtin_amdgcn_s_sleep(64);
    enc = __hip_atomic_load(&s_idx_ws[qid], __ATOMIC_RELAXED,
                            __HIP_MEMORY_SCOPE_AGENT);
  }
  const int sp = __builtin_amdgcn_readfirstlane(enc - 1);
  const int gq = b * NPTS + sp;
  const float qx = coord[(size_t)gq * 3 + 0];
  const float qy = coord[(size_t)gq * 3 + 1];
  const float qz = coord[(size_t)gq * 3 + 2];

  // Per-lane ascending top-8 (value, index), static indexing only.
  float lv[KLANE]; int li[KLANE];
  #pragma unroll
  for (int j = 0; j < KLANE; ++j) { lv[j] = 1e30f; li[j] = 0x7fffffff; }

  // Branchless sorted insert; strict < keeps equal-distance earlier (lower)
  // indices first, matching lax.top_k tie order.
#define INSERT(D2, P) \
  if ((D2) < lv[KLANE - 1]) { \
    _Pragma("unroll") \
    for (int j = KLANE - 1; j >= 1; --j) { \
      bool up = (D2) < lv[j - 1]; \
      float nv = up ? lv[j - 1] : (((D2) < lv[j]) ? (D2) : lv[j]); \
      int   ni = up ? li[j - 1] : (((D2) < lv[j]) ? (P)  : li[j]); \
      lv[j] = nv; li[j] = ni; \
    } \
    if ((D2) < lv[0]) { lv[0] = (D2); li[0] = (P); } \
  }

  for (int s = 0; s < NPTS / 256; ++s) {   // 128 iterations, 4 pts/lane
    int p = (s << 8) | (lane << 2);
    const float4* c4 = (const float4*)(c + (size_t)p * 3);
    float4 f0 = c4[0], f1 = c4[1], f2 = c4[2];
    float dA = dist2f(f0.x, f0.y, f0.z, qx, qy, qz);
    float dB = dist2f(f0.w, f1.x, f1.y, qx, qy, qz);
    float dC = dist2f(f1.z, f1.w, f2.x, qx, qy, qz);
    float dD = dist2f(f2.y, f2.z, f2.w, qx, qy, qz);
    INSERT(dA, p);
    INSERT(dB, p + 1);
    INSERT(dC, p + 2);
    INSERT(dD, p + 3);
  }
#undef INSERT

  // Extract the 32 globally smallest (ascending, tie -> lower index).
  // Round 0 is the query itself (d2 == 0), excluded from the angle mean
  // like angles[:, :, 1:].
  int nbp = 0;
  for (int r = 0; r < GSIZE; ++r) {
    float mv = lv[0]; int mp = li[0];
    #pragma unroll
    for (int m = 1; m < 64; m <<= 1) {
      float ov = __shfl_xor(mv, m, 64);
      int   op = __shfl_xor(mp, m, 64);
      if (ov < mv || (ov == mv && op < mp)) { mv = ov; mp = op; }
    }
    if (lane == r) nbp = mp;
    if (lv[0] == mv && li[0] == mp) {  // unique winner pops its head
      #pragma unroll
      for (int j = 0; j < KLANE - 1; ++j) { lv[j] = lv[j + 1]; li[j] = li[j + 1]; }
      lv[KLANE - 1] = 1e30f; li[KLANE - 1] = 0x7fffffff;
    }
  }

  // Angle for lanes 1..31: theta = 2*atan2(||a*|b| - |a|*b||, ||a*|b| + |a|*b||)
  const float* aRow = feat + (size_t)gq * FDIM;
  float my_a = (lane < FDIM) ? aRow[lane] : 0.0f;

  float ang = 0.0f;
  if (lane >= 1 && lane < GSIZE) {
    const float4* a4 = (const float4*)aRow;
    const float4* b4 = (const float4*)(feat + ((size_t)b * NPTS + nbp) * FDIM);
    float4 av[FDIM / 4], bv[FDIM / 4];
    float aa = 0.0f, bb = 0.0f;
    #pragma unroll
    for (int k = 0; k < FDIM / 4; ++k) {
      av[k] = a4[k]; bv[k] = b4[k];
      aa += av[k].x * av[k].x + av[k].y * av[k].y + av[k].z * av[k].z + av[k].w * av[k].w;
      bb += bv[k].x * bv[k].x + bv[k].y * bv[k].y + bv[k].z * bv[k].z + bv[k].w * bv[k].w;
    }
    float an = sqrtf(aa), bn = sqrtf(bb);
    float num2 = 0.0f, den2 = 0.0f;
    #pragma unroll
    for (int k = 0; k < FDIM / 4; ++k) {
      float n0 = av[k].x * bn - an * bv[k].x, dd0 = av[k].x * bn + an * bv[k].x;
      float n1 = av[k].y * bn - an * bv[k].y, dd1 = av[k].y * bn + an * bv[k].y;
      float n2 = av[k].z * bn - an * bv[k].z, dd2 = av[k].z * bn + an * bv[k].z;
      float n3 = av[k].w * bn - an * bv[k].w, dd3 = av[k].w * bn + an * bv[k].w;
      num2 += n0 * n0 + n1 * n1 + n2 * n2 + n3 * n3;
      den2 += dd0 * dd0 + dd1 * dd1 + dd2 * dd2 + dd3 * dd3;
    }
    ang = 2.0f * atan2f(sqrtf(num2), sqrtf(den2));
  }

  // Wave sum of the 31 angles -> p_curv everywhere.
  float tot = ang;
  #pragma unroll
  for (int m = 1; m < 64; m <<= 1) tot += __shfl_xor(tot, m, 64);
  float p_curv = tot / 31.0f;

  // Outputs (flat concatenation, all as float32).
  float* out_xyz  = out;                              // 8192*3
  float* out_feat = out + (size_t)BATCH * NGROUP * 3; // 8192*33
  float* out_sw   = out_feat + (size_t)BATCH * NGROUP * (FDIM + 1);
  float* out_lab  = out_sw  + (size_t)BATCH * NGROUP;
  float* out_sif  = out_lab + (size_t)BATCH * NGROUP;

  if (lane < FDIM)  out_feat[(size_t)qid * (FDIM + 1) + lane] = my_a;
  if (lane == FDIM) out_feat[(size_t)qid * (FDIM + 1) + FDIM] = p_curv;
  if (lane == 0) {
    out_xyz[(size_t)qid * 3 + 0] = qx;
    out_xyz[(size_t)qid * 3 + 1] = qy;
    out_xyz[(size_t)qid * 3 + 2] = qz;
    out_sw[qid]  = (p_curv > 0.087266f) ? 1.0f : 0.0f;
    out_lab[qid] = (float)labels[gq];
    out_sif[qid] = (float)gq;   // s_idx + b*N
  }
}

extern "C" void kernel_launch(void* const* d_in, const int* in_sizes, int n_in,
                              void* d_out, int out_size, void* d_ws, size_t ws_size,
                              hipStream_t stream) {
  const float* coord  = (const float*)d_in[0];
  const float* feat   = (const float*)d_in[1];
  const int*   labels = (const int*)d_in[2];

  // ws layout: [2][32] u64 ping-pong slots (64B-strided, one line per slot),
  // then [8192] int s_idx (+1 encoded, 0 = unpublished). Both start zeroed.
  unsigned long long* slots = (unsigned long long*)d_ws;
  int* s_idx_ws = (int*)((char*)d_ws +
                         2 * BATCH * NBLK * SLOTSTR * sizeof(unsigned long long));
  const size_t zbytes = 2 * BATCH * NBLK * SLOTSTR * sizeof(unsigned long long)
                      + (size_t)BATCH * NGROUP * sizeof(int);

  hipMemsetAsync(d_ws, 0, zbytes, stream);
  fused_kernel<<<NFPSBLK + NKNNBLK, FTPB, 0, stream>>>(
      coord, feat, labels, slots, s_idx_ws, (float*)d_out);
}